// Round 1
// 1006.012 us; speedup vs baseline: 1.1044x; 1.1044x over previous
//
#include <hip/hip_runtime.h>

#define N_NODES 50000
#define N_EDGES 800000
#define IN_C    512
#define HID_C   256
#define OUT_C   40
#define BN_EPS  1e-5f
#define N_CHUNK ((N_NODES + 255) / 256)   // 196

typedef _Float16 half2v __attribute__((ext_vector_type(2)));
typedef _Float16 half4v __attribute__((ext_vector_type(4)));
typedef _Float16 half8  __attribute__((ext_vector_type(8)));
typedef float    f32x16 __attribute__((ext_vector_type(16)));

// ---------------- static device buffers ----------------
__device__ _Float16 g_h16 [(size_t)N_NODES * HID_C]; // BN+ReLU'd hidden (fp16)
__device__ _Float16 g_Ah  [(size_t)N_NODES * HID_C]; // gemm out (fp16)
__device__ _Float16 g_P   [(size_t)N_NODES * HID_C]; // prop out (fp16, pre-BN)
__device__ _Float16 g_o40h[(size_t)N_NODES * OUT_C]; // out-layer gemm (fp16)
__device__ _Float16 g_l80a[(size_t)N_NODES * 80];    // labels interleaved y1|y2 fp16
__device__ _Float16 g_l80b[(size_t)N_NODES * 80];
__device__ _Float16 g_w0t[HID_C * IN_C];             // W0^T blocked+swizzled [K/32][256][32]
__device__ _Float16 g_w1t[HID_C * HID_C];            // W1^T blocked+swizzled
__device__ _Float16 g_w2t[64 * HID_C];               // W2^T swizzled [64][256]
__device__ float g_deg [N_NODES];
__device__ float g_dinv[N_NODES];
__device__ int   g_cnt [N_NODES];
__device__ int   g_fill[N_NODES];
__device__ int   g_rowptr[N_NODES + 1];
__device__ int   g_colidx[N_EDGES];
__device__ float g_normv [N_EDGES];
__device__ float g_bnstat[4 * HID_C];                // sum0|ss0|sum1|ss1
__device__ float g_bnss  [4 * HID_C];                // scale0|shift0|scale1|shift1
__device__ int   g_csum[256];
__device__ int   g_cpre[256];

// ---------------- graph build ----------------
__global__ void deg_count(const int* __restrict__ row, const float* __restrict__ w) {
    int e = blockIdx.x * blockDim.x + threadIdx.x;
    if (e < N_EDGES) {
        int r = row[e];
        atomicAdd(&g_deg[r], w[e]);
        atomicAdd(&g_cnt[r], 1);
    }
}

__global__ void dinv_kernel() {
    int i = blockIdx.x * blockDim.x + threadIdx.x;
    if (i < N_NODES) {
        float d = g_deg[i] + 1.0f;   // + self-loop weight 1
        g_dinv[i] = (d > 0.f) ? rsqrtf(fmaxf(d, 1e-12f)) : 0.f;
    }
}

__global__ __launch_bounds__(256) void chunk_sum() {
    __shared__ int sh[256];
    int i = blockIdx.x * 256 + threadIdx.x;
    sh[threadIdx.x] = (i < N_NODES) ? g_cnt[i] : 0;
    __syncthreads();
    for (int s = 128; s > 0; s >>= 1) {
        if (threadIdx.x < s) sh[threadIdx.x] += sh[threadIdx.x + s];
        __syncthreads();
    }
    if (threadIdx.x == 0) g_csum[blockIdx.x] = sh[0];
}
__global__ void chunk_scan() {
    int acc = 0;
    for (int b = 0; b < N_CHUNK; ++b) { g_cpre[b] = acc; acc += g_csum[b]; }
    g_rowptr[N_NODES] = acc;
}
__global__ __launch_bounds__(256) void local_scan() {
    __shared__ int woff[4];
    int t = threadIdx.x, lane = t & 63, wv = t >> 6;
    int i = blockIdx.x * 256 + t;
    int v = (i < N_NODES) ? g_cnt[i] : 0;
    int x = v;
    #pragma unroll
    for (int off = 1; off < 64; off <<= 1) {
        int y = __shfl_up(x, off);
        if (lane >= off) x += y;
    }
    if (lane == 63) woff[wv] = x;
    __syncthreads();
    if (t == 0) {
        int a = 0;
        #pragma unroll
        for (int w = 0; w < 4; ++w) { int tmp = woff[w]; woff[w] = a; a += tmp; }
    }
    __syncthreads();
    if (i < N_NODES) g_rowptr[i] = g_cpre[blockIdx.x] + woff[wv] + (x - v);
}

__global__ void fill_kernel(const int* __restrict__ row, const int* __restrict__ col,
                            const float* __restrict__ w) {
    int e = blockIdx.x * blockDim.x + threadIdx.x;
    if (e < N_EDGES) {
        int r = row[e], c = col[e];
        int pos = g_rowptr[r] + atomicAdd(&g_fill[r], 1);
        g_colidx[pos] = c;
        g_normv[pos]  = g_dinv[r] * w[e] * g_dinv[c];
    }
}

// ---------------- conversions ----------------
// W [K][256] fp32 -> blocked+swizzled fp16 panels: tile t=k/32 is a contiguous
// 16KB [256 rows][32 k] slab; within a row the 4 half8-groups are XOR-swizzled
// by (n&3) so ds_read_b128 of a column-slice is bank-spread.
__global__ void wtrans_blk(const float* __restrict__ W, _Float16* __restrict__ dst, int K) {
    int idx = blockIdx.x * blockDim.x + threadIdx.x;
    if (idx >= K * 256) return;
    int k = idx >> 8, n = idx & 255;
    int t = k >> 5, kl = k & 31, g = kl >> 3, j = kl & 7;
    dst[t * 8192 + n * 32 + ((g ^ (n & 3)) << 3) + j] = (_Float16)W[(size_t)k * 256 + n];
}

// W2 [256][40] fp32 -> swizzled fp16 [64 rows][256 k] (rows>=40 zero).
// Row n: 32 half8-groups, group g stored at g^(n&7).
__global__ void wtrans_out(const float* __restrict__ W, _Float16* __restrict__ dst) {
    int idx = blockIdx.x * blockDim.x + threadIdx.x;
    if (idx >= 256 * 64) return;
    int k = idx >> 6, n = idx & 63;
    int g = k >> 3, j = k & 7;
    float v = (n < OUT_C) ? W[(size_t)k * OUT_C + n] : 0.f;
    dst[n * 256 + ((g ^ (n & 7)) << 3) + j] = (_Float16)v;
}

// labels -> interleaved fp16 [i][80] = y1[0..39] | y2[0..39]
__global__ void cvt_lab80(const float* __restrict__ lab1, const float* __restrict__ lab2,
                          _Float16* __restrict__ out) {
    int idx = blockIdx.x * blockDim.x + threadIdx.x;
    if (idx >= N_NODES * 80) return;
    int i = idx / 80, cc = idx - 80 * i;
    float v = (cc < OUT_C) ? lab1[(size_t)i * OUT_C + cc]
                           : lab2[(size_t)i * OUT_C + cc - OUT_C];
    out[idx] = (_Float16)v;
}

// BN scale/shift + ReLU on fp16: g_P -> g_h16
__global__ __launch_bounds__(256) void bn_apply16(const _Float16* __restrict__ h,
                                                  _Float16* __restrict__ out,
                                                  const float* __restrict__ scale,
                                                  const float* __restrict__ shift) {
    int i = blockIdx.x * blockDim.x + threadIdx.x;   // half4-group index
    if (i >= N_NODES * (HID_C / 4)) return;
    int c = (i & 63) * 4;
    half4v v = ((const half4v*)h)[i];
    half4v o;
    o.x = (_Float16)fmaxf((float)v.x * scale[c + 0] + shift[c + 0], 0.f);
    o.y = (_Float16)fmaxf((float)v.y * scale[c + 1] + shift[c + 1], 0.f);
    o.z = (_Float16)fmaxf((float)v.z * scale[c + 2] + shift[c + 2], 0.f);
    o.w = (_Float16)fmaxf((float)v.w * scale[c + 3] + shift[c + 3], 0.f);
    ((half4v*)out)[i] = o;
}

// ---------------- LDS-tiled MFMA GEMM ----------------
// Old reg-only GEMM was L1-transaction-bound: each load was a 64-lane row
// gather touching ~32 cache lines/instruction (~25M transactions for layer 0
// = the whole 138us). Now: A staged coalesced->LDS (pad-40 rows: rows 0..7
// cover all 32 banks exactly once => conflict-free ds_read_b128), B staged via
// global_load_lds from a PRE-SWIZZLED blocked panel (linear dest + inverse-
// swizzled source + swizzled read).
__device__ __forceinline__ half8 load_a8(const _Float16* p) { return *(const half8*)p; }
__device__ __forceinline__ half8 load_a8(const float* p) {
    float4 a0 = *(const float4*)p;
    float4 a1 = *(const float4*)(p + 4);
    half8 h;
    h[0] = (_Float16)a0.x; h[1] = (_Float16)a0.y; h[2] = (_Float16)a0.z; h[3] = (_Float16)a0.w;
    h[4] = (_Float16)a1.x; h[5] = (_Float16)a1.y; h[6] = (_Float16)a1.z; h[7] = (_Float16)a1.w;
    return h;
}

__device__ __forceinline__ void gload_lds16(const _Float16* g, _Float16* l) {
    __builtin_amdgcn_global_load_lds(
        (const __attribute__((address_space(1))) void*)g,
        (__attribute__((address_space(3))) void*)l, 16, 0, 0);
}

// BM=64 x BN=256, BK=32. 4 waves; wave w owns 64-col quarter, acc[2][2].
// A frag: lane = A[m=lane&31][(lane>>5)*8+j]; B frag: lane = BT[n=lane&31][...].
// C/D: col=lane&31, row=(reg&3)+8*(reg>>2)+4*(lane>>5)  [m74/m101-verified].
template <int K, typename AT>
__global__ __launch_bounds__(256) void gemm_t(const AT* __restrict__ A,
                                              const _Float16* __restrict__ Bblk,
                                              _Float16* __restrict__ C, int M) {
    __shared__ _Float16 sA[64 * 40];    // pad 32->40 halves per row
    __shared__ _Float16 sB[256 * 32];   // swizzled blocked tile (16KB)
    int t = threadIdx.x, lane = t & 63, w = t >> 6;
    int l31 = lane & 31, hi = lane >> 5;
    int m0 = blockIdx.x * 64;
    int r = t >> 2, sg = t & 3;
    int arow = min(m0 + r, M - 1);                 // clamp: no OOB reads
    const AT* ap = A + (size_t)arow * K + sg * 8;
    const _Float16* gpb = Bblk + w * 2048 + lane * 8;
    _Float16* lpb = &sB[w * 2048];
    int n0 = w * 64 + l31, n1 = n0 + 32;
    int bo0 = n0 * 32, bo1 = n1 * 32;
    int sw0 = (n0 & 3) << 3, sw1 = (n1 & 3) << 3;

    f32x16 acc[2][2];
    #pragma unroll
    for (int mf = 0; mf < 2; ++mf)
        #pragma unroll
        for (int nf = 0; nf < 2; ++nf)
            #pragma unroll
            for (int s = 0; s < 16; ++s) acc[mf][nf][s] = 0.f;

    for (int k0 = 0; k0 < K; k0 += 32) {
        // B: async global->LDS (coalesced, linear dest)
        const _Float16* gp = gpb + (k0 >> 5) * 8192;
        #pragma unroll
        for (int i = 0; i < 4; ++i)
            gload_lds16(gp + i * 512, lpb + i * 512);
        // A: coalesced reg-stage (+cvt fp32->fp16 for layer 0) -> LDS
        half8 av = load_a8(ap + k0);
        *(half8*)&sA[r * 40 + sg * 8] = av;
        __syncthreads();
        #pragma unroll
        for (int kk = 0; kk < 2; ++kk) {
            int g8 = (kk * 2 + hi) << 3;
            half8 af0 = *(const half8*)&sA[l31 * 40 + g8];
            half8 af1 = *(const half8*)&sA[(l31 + 32) * 40 + g8];
            half8 bf0 = *(const half8*)&sB[bo0 + (g8 ^ sw0)];
            half8 bf1 = *(const half8*)&sB[bo1 + (g8 ^ sw1)];
            acc[0][0] = __builtin_amdgcn_mfma_f32_32x32x16_f16(af0, bf0, acc[0][0], 0, 0, 0);
            acc[0][1] = __builtin_amdgcn_mfma_f32_32x32x16_f16(af0, bf1, acc[0][1], 0, 0, 0);
            acc[1][0] = __builtin_amdgcn_mfma_f32_32x32x16_f16(af1, bf0, acc[1][0], 0, 0, 0);
            acc[1][1] = __builtin_amdgcn_mfma_f32_32x32x16_f16(af1, bf1, acc[1][1], 0, 0, 0);
        }
        __syncthreads();
    }
    int mbase = m0 + 4 * hi;
    #pragma unroll
    for (int mf = 0; mf < 2; ++mf)
        #pragma unroll
        for (int nf = 0; nf < 2; ++nf) {
            int n = w * 64 + nf * 32 + l31;
            #pragma unroll
            for (int rr = 0; rr < 16; ++rr) {
                int m = mbase + mf * 32 + (rr & 3) + 8 * (rr >> 2);
                if (m < M) C[(size_t)m * HID_C + n] = (_Float16)acc[mf][nf][rr];
            }
        }
}

// Out layer: BM=128 (wave w -> 32 rows), N=40 (padded 64). Whole 32KB B panel
// staged to LDS once, A staged per-BK=32 step.
__global__ __launch_bounds__(256) void gemm_out_t(const _Float16* __restrict__ A,
                                                  const _Float16* __restrict__ Bblk,
                                                  _Float16* __restrict__ C, int M) {
    __shared__ _Float16 sB[64 * 256];   // 32KB, swizzled
    __shared__ _Float16 sA[128 * 40];   // 10KB
    const int K = HID_C;
    int t = threadIdx.x, lane = t & 63, w = t >> 6;
    int l31 = lane & 31, hi = lane >> 5;
    int m0 = blockIdx.x * 128;
    {   // stage whole B once (async)
        const _Float16* gp = Bblk + w * 4096 + lane * 8;
        _Float16* lp = &sB[w * 4096];
        #pragma unroll
        for (int i = 0; i < 8; ++i)
            gload_lds16(gp + i * 512, lp + i * 512);
    }
    f32x16 acc[2];
    #pragma unroll
    for (int nf = 0; nf < 2; ++nf)
        #pragma unroll
        for (int s = 0; s < 16; ++s) acc[nf][s] = 0.f;

    for (int k0 = 0; k0 < K; k0 += 32) {
        #pragma unroll
        for (int u = 0; u < 2; ++u) {
            int uu = t + u * 256;
            int r = uu >> 2, sg = uu & 3;
            int arow = min(m0 + r, M - 1);
            half8 av = *(const half8*)(A + (size_t)arow * K + k0 + sg * 8);
            *(half8*)&sA[r * 40 + sg * 8] = av;
        }
        __syncthreads();
        #pragma unroll
        for (int kk = 0; kk < 2; ++kk) {
            int gloc = kk * 2 + hi;
            int g = (k0 >> 3) + gloc;
            half8 af = *(const half8*)&sA[(w * 32 + l31) * 40 + gloc * 8];
            #pragma unroll
            for (int nf = 0; nf < 2; ++nf) {
                int n = nf * 32 + l31;
                half8 bf = *(const half8*)&sB[n * 256 + ((g ^ (n & 7)) << 3)];
                acc[nf] = __builtin_amdgcn_mfma_f32_32x32x16_f16(af, bf, acc[nf], 0, 0, 0);
            }
        }
        __syncthreads();
    }
    int mbase = m0 + w * 32 + 4 * hi;
    #pragma unroll
    for (int nf = 0; nf < 2; ++nf) {
        int n = nf * 32 + l31;
        if (n < OUT_C) {
            #pragma unroll
            for (int rr = 0; rr < 16; ++rr) {
                int m = mbase + (rr & 3) + 8 * (rr >> 2);
                if (m < M) C[(size_t)m * OUT_C + n] = (_Float16)acc[nf][rr];
            }
        }
    }
}

// ---------------- propagation (fp16 gathers, fp32 accumulate, fp16 out) ------
// wave per node, lane = 4 channels (half4 = 8 B); 4 nodes/block
__global__ __launch_bounds__(256) void prop256h(const _Float16* __restrict__ h,
                                                _Float16* __restrict__ out,
                                                const float* __restrict__ bias) {
    int wv = threadIdx.x >> 6, lane = threadIdx.x & 63;
    int i = blockIdx.x * 4 + wv;               // grid = 12500 exact
    const half4v* hv = (const half4v*)h;
    float di = g_dinv[i], d2 = di * di;
    half4v r = hv[(size_t)i * 64 + lane];
    float4 acc = make_float4(d2 * (float)r.x, d2 * (float)r.y,
                             d2 * (float)r.z, d2 * (float)r.w);
    int s = g_rowptr[i], e = g_rowptr[i + 1];
    for (int k = s; k < e; ++k) {
        int   j  = g_colidx[k];
        float nv = g_normv[k];
        half4v v = hv[(size_t)j * 64 + lane];
        acc.x += nv * (float)v.x; acc.y += nv * (float)v.y;
        acc.z += nv * (float)v.z; acc.w += nv * (float)v.w;
    }
    float4 b = ((const float4*)bias)[lane];
    half4v o;
    o.x = (_Float16)(acc.x + b.x); o.y = (_Float16)(acc.y + b.y);
    o.z = (_Float16)(acc.z + b.z); o.w = (_Float16)(acc.w + b.w);
    ((half4v*)out)[(size_t)i * 64 + lane] = o;
}

// GCN output: fp16 input [M][40], fp32 output (+bias) to d_out
__global__ __launch_bounds__(256) void prop40h(const _Float16* __restrict__ h,
                                               float* __restrict__ out,
                                               const float* __restrict__ bias) {
    int wv = threadIdx.x >> 6, lane = threadIdx.x & 63;
    if (lane >= OUT_C) return;
    int i = blockIdx.x * 4 + wv;
    float di = g_dinv[i];
    float acc = di * di * (float)h[(size_t)i * OUT_C + lane];
    int s = g_rowptr[i], e = g_rowptr[i + 1];
    for (int k = s; k < e; ++k)
        acc += g_normv[k] * (float)h[(size_t)g_colidx[k] * OUT_C + lane];
    out[(size_t)i * OUT_C + lane] = acc + bias[lane];
}

// paired label propagation on interleaved fp16 [i][80]; lane = half2 (2 chans)
template <bool FINAL>
__global__ __launch_bounds__(256) void prop80(const _Float16* __restrict__ y,
                                              _Float16* __restrict__ o,
                                              float* __restrict__ o1,
                                              float* __restrict__ o2) {
    int wv = threadIdx.x >> 6, lane = threadIdx.x & 63;
    if (lane >= 40) return;
    int i = blockIdx.x * 4 + wv;
    const half2v* yp = (const half2v*)y;
    float di = g_dinv[i], d2 = di * di;
    half2v sv = yp[(size_t)i * 40 + lane];
    float a0 = d2 * (float)sv.x, a1 = d2 * (float)sv.y;
    int ks = g_rowptr[i], ke = g_rowptr[i + 1];
    for (int k = ks; k < ke; ++k) {
        int   j  = g_colidx[k];
        float nv = g_normv[k];
        half2v v = yp[(size_t)j * 40 + lane];
        a0 += nv * (float)v.x; a1 += nv * (float)v.y;
    }
    if (FINAL) {
        int cc = lane * 2;
        float vals[2] = {a0, a1};
        #pragma unroll
        for (int t = 0; t < 2; ++t) {
            int c = cc + t;
            if (c < OUT_C) o1[(size_t)i * OUT_C + c] = vals[t];
            else           o2[(size_t)i * OUT_C + (c - OUT_C)] = vals[t];
        }
    } else {
        half2v ov; ov.x = (_Float16)a0; ov.y = (_Float16)a1;
        ((half2v*)o)[(size_t)i * 40 + lane] = ov;
    }
}

// ---------------- batchnorm stats (fp16 input, 32 rows/block) ----------------
__global__ __launch_bounds__(256) void bn_stats16(const _Float16* __restrict__ h, int layer) {
    int c = threadIdx.x;
    int r0 = blockIdx.x * 32;
    int rend = min(r0 + 32, N_NODES);
    float s = 0.f, ss = 0.f;
    for (int i = r0; i < rend; ++i) {
        float v = (float)h[(size_t)i * HID_C + c];
        s += v; ss += v * v;
    }
    atomicAdd(&g_bnstat[layer * 512 + c], s);
    atomicAdd(&g_bnstat[layer * 512 + 256 + c], ss);
}

__global__ void bn_final(int layer, const float* __restrict__ gamma,
                         const float* __restrict__ beta) {
    int c = threadIdx.x;
    float sum = g_bnstat[layer * 512 + c];
    float ss  = g_bnstat[layer * 512 + 256 + c];
    float mu  = sum / (float)N_NODES;
    float var = fmaxf(ss / (float)N_NODES - mu * mu, 0.f);
    float scale = gamma[c] * rsqrtf(var + BN_EPS);
    g_bnss[layer * 512 + c]       = scale;
    g_bnss[layer * 512 + 256 + c] = beta[c] - mu * scale;
}

// ---------------- host ----------------
template <typename T>
static T* symaddr(const void* sym) {
    void* p = nullptr;
    (void)hipGetSymbolAddress(&p, sym);
    return (T*)p;
}

extern "C" void kernel_launch(void* const* d_in, const int* in_sizes, int n_in,
                              void* d_out, int out_size, void* d_ws, size_t ws_size,
                              hipStream_t stream) {
    const float* x    = (const float*)d_in[0];
    const int*   ei   = (const int*)d_in[1];
    const float* lab1 = (const float*)d_in[2];
    const float* lab2 = (const float*)d_in[3];
    const float* ew   = (const float*)d_in[4];
    const float* W0   = (const float*)d_in[5];
    const float* b0   = (const float*)d_in[6];
    const float* W1   = (const float*)d_in[7];
    const float* b1   = (const float*)d_in[8];
    const float* W2   = (const float*)d_in[9];
    const float* b2   = (const float*)d_in[10];
    const float* gg0  = (const float*)d_in[11];
    const float* be0  = (const float*)d_in[12];
    const float* gg1  = (const float*)d_in[13];
    const float* be1  = (const float*)d_in[14];

    _Float16* ph16 = symaddr<_Float16>(HIP_SYMBOL(g_h16));
    _Float16* pAh  = symaddr<_Float16>(HIP_SYMBOL(g_Ah));
    _Float16* pP   = symaddr<_Float16>(HIP_SYMBOL(g_P));
    _Float16* po40 = symaddr<_Float16>(HIP_SYMBOL(g_o40h));
    _Float16* pl80a= symaddr<_Float16>(HIP_SYMBOL(g_l80a));
    _Float16* pl80b= symaddr<_Float16>(HIP_SYMBOL(g_l80b));
    _Float16* pw0t = symaddr<_Float16>(HIP_SYMBOL(g_w0t));
    _Float16* pw1t = symaddr<_Float16>(HIP_SYMBOL(g_w1t));
    _Float16* pw2t = symaddr<_Float16>(HIP_SYMBOL(g_w2t));
    float* pdeg = symaddr<float>(HIP_SYMBOL(g_deg));
    int*   pcnt = symaddr<int>(HIP_SYMBOL(g_cnt));
    int*   pfil = symaddr<int>(HIP_SYMBOL(g_fill));
    float* pbst = symaddr<float>(HIP_SYMBOL(g_bnstat));
    float* pbss = symaddr<float>(HIP_SYMBOL(g_bnss));

    hipMemsetAsync(pdeg, 0, N_NODES * sizeof(float), stream);
    hipMemsetAsync(pcnt, 0, N_NODES * sizeof(int),   stream);
    hipMemsetAsync(pfil, 0, N_NODES * sizeof(int),   stream);
    hipMemsetAsync(pbst, 0, 4 * HID_C * sizeof(float), stream);

    // CSR build
    const int EB = (N_EDGES + 255) / 256;
    deg_count<<<EB, 256, 0, stream>>>(ei, ew);
    dinv_kernel<<<(N_NODES + 255) / 256, 256, 0, stream>>>();
    chunk_sum<<<N_CHUNK, 256, 0, stream>>>();
    chunk_scan<<<1, 1, 0, stream>>>();
    local_scan<<<N_CHUNK, 256, 0, stream>>>();
    fill_kernel<<<EB, 256, 0, stream>>>(ei, ei + N_EDGES, ew);

    // weight transposes (blocked+swizzled) + label interleave
    wtrans_blk<<<(IN_C * 256 + 255) / 256, 256, 0, stream>>>(W0, pw0t, IN_C);
    wtrans_blk<<<(HID_C * 256 + 255) / 256, 256, 0, stream>>>(W1, pw1t, HID_C);
    wtrans_out<<<(256 * 64 + 255) / 256, 256, 0, stream>>>(W2, pw2t);
    cvt_lab80<<<(N_NODES * 80 + 255) / 256, 256, 0, stream>>>(lab1, lab2, pl80a);

    const int GT   = (N_NODES + 63) / 128 * 2 + ((N_NODES % 64) ? 1 : 0); // see below
    const int GT64 = (N_NODES + 63) / 64;    // 782
    const int GO   = (N_NODES + 127) / 128;  // 391
    const int GB32 = (N_NODES + 31) / 32;    // 1563
    const int PB   = N_NODES / 4;            // 12500
    const int CB   = (N_NODES * 64 + 255) / 256;
    (void)GT;
    float* outf = (float*)d_out;    // fp32: out | y_hat | y_hat2

    // layer 0 (A = x fp32, converted in-register during staging)
    gemm_t<IN_C, float><<<GT64, 256, 0, stream>>>(x, pw0t, pAh, N_NODES);
    prop256h<<<PB, 256, 0, stream>>>(pAh, pP, b0);
    bn_stats16<<<GB32, 256, 0, stream>>>(pP, 0);
    bn_final<<<1, 256, 0, stream>>>(0, gg0, be0);
    bn_apply16<<<CB, 256, 0, stream>>>(pP, ph16, pbss, pbss + 256);

    // layer 1
    gemm_t<HID_C, _Float16><<<GT64, 256, 0, stream>>>(ph16, pw1t, pAh, N_NODES);
    prop256h<<<PB, 256, 0, stream>>>(pAh, pP, b1);
    bn_stats16<<<GB32, 256, 0, stream>>>(pP, 1);
    bn_final<<<1, 256, 0, stream>>>(1, gg1, be1);
    bn_apply16<<<CB, 256, 0, stream>>>(pP, ph16, pbss + 512, pbss + 768);

    // layer 2
    gemm_out_t<<<GO, 256, 0, stream>>>(ph16, pw2t, po40, N_NODES);
    prop40h<<<PB, 256, 0, stream>>>(po40, outf, b2);

    // label propagation x3 (both matrices per pass, interleaved fp16)
    prop80<false><<<PB, 256, 0, stream>>>(pl80a, pl80b, nullptr, nullptr);
    prop80<false><<<PB, 256, 0, stream>>>(pl80b, pl80a, nullptr, nullptr);
    prop80<true ><<<PB, 256, 0, stream>>>(pl80a, nullptr,
                                          outf + (size_t)N_NODES * OUT_C,
                                          outf + 2 * (size_t)N_NODES * OUT_C);
}

// Round 3
// 788.883 us; speedup vs baseline: 1.4084x; 1.2752x over previous
//
#include <hip/hip_runtime.h>

#define N_NODES 50000
#define N_EDGES 800000
#define IN_C    512
#define HID_C   256
#define OUT_C   40
#define BN_EPS  1e-5f
#define N_CHUNK ((N_NODES + 255) / 256)   // 196

typedef _Float16 half2v __attribute__((ext_vector_type(2)));
typedef _Float16 half4v __attribute__((ext_vector_type(4)));
typedef _Float16 half8  __attribute__((ext_vector_type(8)));
typedef float    f32x16 __attribute__((ext_vector_type(16)));

// ---------------- static device buffers ----------------
__device__ _Float16 g_h16 [(size_t)N_NODES * HID_C]; // BN+ReLU'd hidden (fp16)
__device__ _Float16 g_Ah  [(size_t)N_NODES * HID_C]; // gemm out (fp16)
__device__ _Float16 g_P   [(size_t)N_NODES * HID_C]; // prop out (fp16, pre-BN)
__device__ _Float16 g_o40h[(size_t)N_NODES * OUT_C]; // out-layer gemm (fp16)
__device__ _Float16 g_l80a[(size_t)N_NODES * 80];    // labels interleaved y1|y2 fp16
__device__ _Float16 g_l80b[(size_t)N_NODES * 80];
__device__ _Float16 g_w0t[HID_C * IN_C];             // W0^T blocked+swizzled [K/32][256][32]
__device__ _Float16 g_w1t[HID_C * HID_C];            // W1^T blocked+swizzled
__device__ _Float16 g_w2t[64 * HID_C];               // W2^T swizzled [64][256]
__device__ float g_deg [N_NODES];
__device__ float g_dinv[N_NODES];
__device__ int   g_cnt [N_NODES];
__device__ int   g_fill[N_NODES];
__device__ int   g_rowptr[N_NODES + 1];
__device__ int2  g_edge[N_EDGES];                    // packed (col, norm-as-bits)
__device__ float g_bnstat[4 * HID_C];                // sum0|ss0|sum1|ss1
__device__ float g_bnss  [4 * HID_C];                // scale0|shift0|scale1|shift1
__device__ int   g_csum[256];
__device__ int   g_cpre[256];

// ---------------- graph build ----------------
__global__ void deg_count(const int* __restrict__ row, const float* __restrict__ w) {
    int e = blockIdx.x * blockDim.x + threadIdx.x;
    if (e < N_EDGES) {
        int r = row[e];
        atomicAdd(&g_deg[r], w[e]);
        atomicAdd(&g_cnt[r], 1);
    }
}

__global__ void dinv_kernel() {
    int i = blockIdx.x * blockDim.x + threadIdx.x;
    if (i < N_NODES) {
        float d = g_deg[i] + 1.0f;   // + self-loop weight 1
        g_dinv[i] = (d > 0.f) ? rsqrtf(fmaxf(d, 1e-12f)) : 0.f;
    }
}

__global__ __launch_bounds__(256) void chunk_sum() {
    __shared__ int sh[256];
    int i = blockIdx.x * 256 + threadIdx.x;
    sh[threadIdx.x] = (i < N_NODES) ? g_cnt[i] : 0;
    __syncthreads();
    for (int s = 128; s > 0; s >>= 1) {
        if (threadIdx.x < s) sh[threadIdx.x] += sh[threadIdx.x + s];
        __syncthreads();
    }
    if (threadIdx.x == 0) g_csum[blockIdx.x] = sh[0];
}
__global__ void chunk_scan() {
    int acc = 0;
    for (int b = 0; b < N_CHUNK; ++b) { g_cpre[b] = acc; acc += g_csum[b]; }
    g_rowptr[N_NODES] = acc;
}
__global__ __launch_bounds__(256) void local_scan() {
    __shared__ int woff[4];
    int t = threadIdx.x, lane = t & 63, wv = t >> 6;
    int i = blockIdx.x * 256 + t;
    int v = (i < N_NODES) ? g_cnt[i] : 0;
    int x = v;
    #pragma unroll
    for (int off = 1; off < 64; off <<= 1) {
        int y = __shfl_up(x, off);
        if (lane >= off) x += y;
    }
    if (lane == 63) woff[wv] = x;
    __syncthreads();
    if (t == 0) {
        int a = 0;
        #pragma unroll
        for (int w = 0; w < 4; ++w) { int tmp = woff[w]; woff[w] = a; a += tmp; }
    }
    __syncthreads();
    if (i < N_NODES) g_rowptr[i] = g_cpre[blockIdx.x] + woff[wv] + (x - v);
}

__global__ void fill_kernel(const int* __restrict__ row, const int* __restrict__ col,
                            const float* __restrict__ w) {
    int e = blockIdx.x * blockDim.x + threadIdx.x;
    if (e < N_EDGES) {
        int r = row[e], c = col[e];
        int pos = g_rowptr[r] + atomicAdd(&g_fill[r], 1);
        float nv = g_dinv[r] * w[e] * g_dinv[c];
        g_edge[pos] = make_int2(c, __float_as_int(nv));
    }
}

// ---------------- conversions ----------------
// W [K][256] fp32 -> blocked+swizzled fp16 panels: tile t=k/32 is a contiguous
// 16KB [256 rows][32 k] slab; within a row the 4 half8-groups are XOR-swizzled
// by (n&3) so ds_read_b128 of a column-slice is bank-spread.
__global__ void wtrans_blk(const float* __restrict__ W, _Float16* __restrict__ dst, int K) {
    int idx = blockIdx.x * blockDim.x + threadIdx.x;
    if (idx >= K * 256) return;
    int k = idx >> 8, n = idx & 255;
    int t = k >> 5, kl = k & 31, g = kl >> 3, j = kl & 7;
    dst[t * 8192 + n * 32 + ((g ^ (n & 3)) << 3) + j] = (_Float16)W[(size_t)k * 256 + n];
}

// W2 [256][40] fp32 -> swizzled fp16 [64 rows][256 k] (rows>=40 zero).
// Row n: 32 half8-groups, group g stored at g^(n&7).
__global__ void wtrans_out(const float* __restrict__ W, _Float16* __restrict__ dst) {
    int idx = blockIdx.x * blockDim.x + threadIdx.x;
    if (idx >= 256 * 64) return;
    int k = idx >> 6, n = idx & 63;
    int g = k >> 3, j = k & 7;
    float v = (n < OUT_C) ? W[(size_t)k * OUT_C + n] : 0.f;
    dst[n * 256 + ((g ^ (n & 7)) << 3) + j] = (_Float16)v;
}

// labels -> interleaved fp16 [i][80] = y1[0..39] | y2[0..39]
__global__ void cvt_lab80(const float* __restrict__ lab1, const float* __restrict__ lab2,
                          _Float16* __restrict__ out) {
    int idx = blockIdx.x * blockDim.x + threadIdx.x;
    if (idx >= N_NODES * 80) return;
    int i = idx / 80, cc = idx - 80 * i;
    float v = (cc < OUT_C) ? lab1[(size_t)i * OUT_C + cc]
                           : lab2[(size_t)i * OUT_C + cc - OUT_C];
    out[idx] = (_Float16)v;
}

// BN scale/shift + ReLU on fp16: g_P -> g_h16
__global__ __launch_bounds__(256) void bn_apply16(const _Float16* __restrict__ h,
                                                  _Float16* __restrict__ out,
                                                  const float* __restrict__ scale,
                                                  const float* __restrict__ shift) {
    int i = blockIdx.x * blockDim.x + threadIdx.x;   // half4-group index
    if (i >= N_NODES * (HID_C / 4)) return;
    int c = (i & 63) * 4;
    half4v v = ((const half4v*)h)[i];
    half4v o;
    o.x = (_Float16)fmaxf((float)v.x * scale[c + 0] + shift[c + 0], 0.f);
    o.y = (_Float16)fmaxf((float)v.y * scale[c + 1] + shift[c + 1], 0.f);
    o.z = (_Float16)fmaxf((float)v.z * scale[c + 2] + shift[c + 2], 0.f);
    o.w = (_Float16)fmaxf((float)v.w * scale[c + 3] + shift[c + 3], 0.f);
    ((half4v*)out)[i] = o;
}

// ---------------- LDS-tiled MFMA GEMM ----------------
// A staged coalesced->LDS (pad-40 rows => conflict-free ds_read_b128), B staged
// via global_load_lds from a PRE-SWIZZLED blocked panel (linear dest +
// inverse-swizzled source + swizzled read).
__device__ __forceinline__ half8 load_a8(const _Float16* p) { return *(const half8*)p; }
__device__ __forceinline__ half8 load_a8(const float* p) {
    float4 a0 = *(const float4*)p;
    float4 a1 = *(const float4*)(p + 4);
    half8 h;
    h[0] = (_Float16)a0.x; h[1] = (_Float16)a0.y; h[2] = (_Float16)a0.z; h[3] = (_Float16)a0.w;
    h[4] = (_Float16)a1.x; h[5] = (_Float16)a1.y; h[6] = (_Float16)a1.z; h[7] = (_Float16)a1.w;
    return h;
}

__device__ __forceinline__ void gload_lds16(const _Float16* g, _Float16* l) {
    __builtin_amdgcn_global_load_lds(
        (const __attribute__((address_space(1))) void*)g,
        (__attribute__((address_space(3))) void*)l, 16, 0, 0);
}

// BM=64 x BN=256, BK=32. 4 waves; wave w owns 64-col quarter, acc[2][2].
// C/D: col=lane&31, row=(reg&3)+8*(reg>>2)+4*(lane>>5)  [m74/m101-verified].
template <int K, typename AT>
__global__ __launch_bounds__(256) void gemm_t(const AT* __restrict__ A,
                                              const _Float16* __restrict__ Bblk,
                                              _Float16* __restrict__ C, int M) {
    __shared__ _Float16 sA[64 * 40];    // pad 32->40 halves per row
    __shared__ _Float16 sB[256 * 32];   // swizzled blocked tile (16KB)
    int t = threadIdx.x, lane = t & 63, w = t >> 6;
    int l31 = lane & 31, hi = lane >> 5;
    int m0 = blockIdx.x * 64;
    int r = t >> 2, sg = t & 3;
    int arow = min(m0 + r, M - 1);                 // clamp: no OOB reads
    const AT* ap = A + (size_t)arow * K + sg * 8;
    const _Float16* gpb = Bblk + w * 2048 + lane * 8;
    _Float16* lpb = &sB[w * 2048];
    int n0 = w * 64 + l31, n1 = n0 + 32;
    int bo0 = n0 * 32, bo1 = n1 * 32;
    int sw0 = (n0 & 3) << 3, sw1 = (n1 & 3) << 3;

    f32x16 acc[2][2];
    #pragma unroll
    for (int mf = 0; mf < 2; ++mf)
        #pragma unroll
        for (int nf = 0; nf < 2; ++nf)
            #pragma unroll
            for (int s = 0; s < 16; ++s) acc[mf][nf][s] = 0.f;

    for (int k0 = 0; k0 < K; k0 += 32) {
        // B: async global->LDS (coalesced, linear dest)
        const _Float16* gp = gpb + (k0 >> 5) * 8192;
        #pragma unroll
        for (int i = 0; i < 4; ++i)
            gload_lds16(gp + i * 512, lpb + i * 512);
        // A: coalesced reg-stage (+cvt fp32->fp16 for layer 0) -> LDS
        half8 av = load_a8(ap + k0);
        *(half8*)&sA[r * 40 + sg * 8] = av;
        __syncthreads();
        #pragma unroll
        for (int kk = 0; kk < 2; ++kk) {
            int g8 = (kk * 2 + hi) << 3;
            half8 af0 = *(const half8*)&sA[l31 * 40 + g8];
            half8 af1 = *(const half8*)&sA[(l31 + 32) * 40 + g8];
            half8 bf0 = *(const half8*)&sB[bo0 + (g8 ^ sw0)];
            half8 bf1 = *(const half8*)&sB[bo1 + (g8 ^ sw1)];
            acc[0][0] = __builtin_amdgcn_mfma_f32_32x32x16_f16(af0, bf0, acc[0][0], 0, 0, 0);
            acc[0][1] = __builtin_amdgcn_mfma_f32_32x32x16_f16(af0, bf1, acc[0][1], 0, 0, 0);
            acc[1][0] = __builtin_amdgcn_mfma_f32_32x32x16_f16(af1, bf0, acc[1][0], 0, 0, 0);
            acc[1][1] = __builtin_amdgcn_mfma_f32_32x32x16_f16(af1, bf1, acc[1][1], 0, 0, 0);
        }
        __syncthreads();
    }
    int mbase = m0 + 4 * hi;
    #pragma unroll
    for (int mf = 0; mf < 2; ++mf)
        #pragma unroll
        for (int nf = 0; nf < 2; ++nf) {
            int n = w * 64 + nf * 32 + l31;
            #pragma unroll
            for (int rr = 0; rr < 16; ++rr) {
                int m = mbase + mf * 32 + (rr & 3) + 8 * (rr >> 2);
                if (m < M) C[(size_t)m * HID_C + n] = (_Float16)acc[mf][nf][rr];
            }
        }
}

// Out layer: BM=128 (wave w -> 32 rows), N=40 (padded 64). Whole 32KB B panel
// staged to LDS once, A staged per-BK=32 step.
__global__ __launch_bounds__(256) void gemm_out_t(const _Float16* __restrict__ A,
                                                  const _Float16* __restrict__ Bblk,
                                                  _Float16* __restrict__ C, int M) {
    __shared__ _Float16 sB[64 * 256];   // 32KB, swizzled
    __shared__ _Float16 sA[128 * 40];   // 10KB
    const int K = HID_C;
    int t = threadIdx.x, lane = t & 63, w = t >> 6;
    int l31 = lane & 31, hi = lane >> 5;
    int m0 = blockIdx.x * 128;
    {   // stage whole B once (async)
        const _Float16* gp = Bblk + w * 4096 + lane * 8;
        _Float16* lp = &sB[w * 4096];
        #pragma unroll
        for (int i = 0; i < 8; ++i)
            gload_lds16(gp + i * 512, lp + i * 512);
    }
    f32x16 acc[2];
    #pragma unroll
    for (int nf = 0; nf < 2; ++nf)
        #pragma unroll
        for (int s = 0; s < 16; ++s) acc[nf][s] = 0.f;

    for (int k0 = 0; k0 < K; k0 += 32) {
        #pragma unroll
        for (int u = 0; u < 2; ++u) {
            int uu = t + u * 256;
            int r = uu >> 2, sg = uu & 3;
            int arow = min(m0 + r, M - 1);
            half8 av = *(const half8*)(A + (size_t)arow * K + k0 + sg * 8);
            *(half8*)&sA[r * 40 + sg * 8] = av;
        }
        __syncthreads();
        #pragma unroll
        for (int kk = 0; kk < 2; ++kk) {
            int gloc = kk * 2 + hi;
            int g = (k0 >> 3) + gloc;
            half8 af = *(const half8*)&sA[(w * 32 + l31) * 40 + gloc * 8];
            #pragma unroll
            for (int nf = 0; nf < 2; ++nf) {
                int n = nf * 32 + l31;
                half8 bf = *(const half8*)&sB[n * 256 + ((g ^ (n & 7)) << 3)];
                acc[nf] = __builtin_amdgcn_mfma_f32_32x32x16_f16(af, bf, acc[nf], 0, 0, 0);
            }
        }
        __syncthreads();
    }
    int mbase = m0 + w * 32 + 4 * hi;
    #pragma unroll
    for (int nf = 0; nf < 2; ++nf) {
        int n = nf * 32 + l31;
        if (n < OUT_C) {
            #pragma unroll
            for (int rr = 0; rr < 16; ++rr) {
                int m = mbase + (rr & 3) + 8 * (rr >> 2);
                if (m < M) C[(size_t)m * OUT_C + n] = (_Float16)acc[nf][rr];
            }
        }
    }
}

// ---------------- propagation (fp16 gathers, fp32 accumulate, fp16 out) ------
// wave per node, lane = 4 channels (half4 = 8 B); 4 nodes/block.
// MLP-4: load 4 packed edge records, issue 4 independent row gathers.
__global__ __launch_bounds__(256) void prop256h(const _Float16* __restrict__ h,
                                                _Float16* __restrict__ out,
                                                const float* __restrict__ bias) {
    int wv = threadIdx.x >> 6, lane = threadIdx.x & 63;
    int i = blockIdx.x * 4 + wv;               // grid = 12500 exact
    const half4v* hv = (const half4v*)h;
    float di = g_dinv[i], d2 = di * di;
    half4v r = hv[(size_t)i * 64 + lane];
    float4 acc = make_float4(d2 * (float)r.x, d2 * (float)r.y,
                             d2 * (float)r.z, d2 * (float)r.w);
    int s = g_rowptr[i], e = g_rowptr[i + 1];
    int k = s;
    for (; k + 4 <= e; k += 4) {
        int2 e0 = g_edge[k], e1 = g_edge[k + 1], e2 = g_edge[k + 2], e3 = g_edge[k + 3];
        half4v v0 = hv[(size_t)e0.x * 64 + lane];
        half4v v1 = hv[(size_t)e1.x * 64 + lane];
        half4v v2 = hv[(size_t)e2.x * 64 + lane];
        half4v v3 = hv[(size_t)e3.x * 64 + lane];
        float n0 = __int_as_float(e0.y), n1 = __int_as_float(e1.y);
        float n2 = __int_as_float(e2.y), n3 = __int_as_float(e3.y);
        acc.x += n0 * (float)v0.x + n1 * (float)v1.x + n2 * (float)v2.x + n3 * (float)v3.x;
        acc.y += n0 * (float)v0.y + n1 * (float)v1.y + n2 * (float)v2.y + n3 * (float)v3.y;
        acc.z += n0 * (float)v0.z + n1 * (float)v1.z + n2 * (float)v2.z + n3 * (float)v3.z;
        acc.w += n0 * (float)v0.w + n1 * (float)v1.w + n2 * (float)v2.w + n3 * (float)v3.w;
    }
    for (; k < e; ++k) {
        int2 ed = g_edge[k];
        float nv = __int_as_float(ed.y);
        half4v v = hv[(size_t)ed.x * 64 + lane];
        acc.x += nv * (float)v.x; acc.y += nv * (float)v.y;
        acc.z += nv * (float)v.z; acc.w += nv * (float)v.w;
    }
    float4 b = ((const float4*)bias)[lane];
    half4v o;
    o.x = (_Float16)(acc.x + b.x); o.y = (_Float16)(acc.y + b.y);
    o.z = (_Float16)(acc.z + b.z); o.w = (_Float16)(acc.w + b.w);
    ((half4v*)out)[(size_t)i * 64 + lane] = o;
}

// GCN output: fp16 input [M][40], fp32 output (+bias) to d_out
__global__ __launch_bounds__(256) void prop40h(const _Float16* __restrict__ h,
                                               float* __restrict__ out,
                                               const float* __restrict__ bias) {
    int wv = threadIdx.x >> 6, lane = threadIdx.x & 63;
    if (lane >= OUT_C) return;
    int i = blockIdx.x * 4 + wv;
    float di = g_dinv[i];
    float acc = di * di * (float)h[(size_t)i * OUT_C + lane];
    int s = g_rowptr[i], e = g_rowptr[i + 1];
    int k = s;
    for (; k + 4 <= e; k += 4) {
        int2 e0 = g_edge[k], e1 = g_edge[k + 1], e2 = g_edge[k + 2], e3 = g_edge[k + 3];
        float v0 = (float)h[(size_t)e0.x * OUT_C + lane];
        float v1 = (float)h[(size_t)e1.x * OUT_C + lane];
        float v2 = (float)h[(size_t)e2.x * OUT_C + lane];
        float v3 = (float)h[(size_t)e3.x * OUT_C + lane];
        acc += __int_as_float(e0.y) * v0 + __int_as_float(e1.y) * v1
             + __int_as_float(e2.y) * v2 + __int_as_float(e3.y) * v3;
    }
    for (; k < e; ++k) {
        int2 ed = g_edge[k];
        acc += __int_as_float(ed.y) * (float)h[(size_t)ed.x * OUT_C + lane];
    }
    out[(size_t)i * OUT_C + lane] = acc + bias[lane];
}

// paired label propagation on interleaved fp16 [i][80]; lane = half2 (2 chans)
template <bool FINAL>
__global__ __launch_bounds__(256) void prop80(const _Float16* __restrict__ y,
                                              _Float16* __restrict__ o,
                                              float* __restrict__ o1,
                                              float* __restrict__ o2) {
    int wv = threadIdx.x >> 6, lane = threadIdx.x & 63;
    if (lane >= 40) return;
    int i = blockIdx.x * 4 + wv;
    const half2v* yp = (const half2v*)y;
    float di = g_dinv[i], d2 = di * di;
    half2v sv = yp[(size_t)i * 40 + lane];
    float a0 = d2 * (float)sv.x, a1 = d2 * (float)sv.y;
    int ks = g_rowptr[i], ke = g_rowptr[i + 1];
    int k = ks;
    for (; k + 4 <= ke; k += 4) {
        int2 e0 = g_edge[k], e1 = g_edge[k + 1], e2 = g_edge[k + 2], e3 = g_edge[k + 3];
        half2v v0 = yp[(size_t)e0.x * 40 + lane];
        half2v v1 = yp[(size_t)e1.x * 40 + lane];
        half2v v2 = yp[(size_t)e2.x * 40 + lane];
        half2v v3 = yp[(size_t)e3.x * 40 + lane];
        float n0 = __int_as_float(e0.y), n1 = __int_as_float(e1.y);
        float n2 = __int_as_float(e2.y), n3 = __int_as_float(e3.y);
        a0 += n0 * (float)v0.x + n1 * (float)v1.x + n2 * (float)v2.x + n3 * (float)v3.x;
        a1 += n0 * (float)v0.y + n1 * (float)v1.y + n2 * (float)v2.y + n3 * (float)v3.y;
    }
    for (; k < ke; ++k) {
        int2 ed = g_edge[k];
        float nv = __int_as_float(ed.y);
        half2v v = yp[(size_t)ed.x * 40 + lane];
        a0 += nv * (float)v.x; a1 += nv * (float)v.y;
    }
    if (FINAL) {
        int cc = lane * 2;
        float vals[2] = {a0, a1};
        #pragma unroll
        for (int t = 0; t < 2; ++t) {
            int c = cc + t;
            if (c < OUT_C) o1[(size_t)i * OUT_C + c] = vals[t];
            else           o2[(size_t)i * OUT_C + (c - OUT_C)] = vals[t];
        }
    } else {
        half2v ov; ov.x = (_Float16)a0; ov.y = (_Float16)a1;
        ((half2v*)o)[(size_t)i * 40 + lane] = ov;
    }
}

// ---------------- batchnorm stats (fp16 input, 32 rows/block) ----------------
__global__ __launch_bounds__(256) void bn_stats16(const _Float16* __restrict__ h, int layer) {
    int c = threadIdx.x;
    int r0 = blockIdx.x * 32;
    int rend = min(r0 + 32, N_NODES);
    float s = 0.f, ss = 0.f;
    for (int i = r0; i < rend; ++i) {
        float v = (float)h[(size_t)i * HID_C + c];
        s += v; ss += v * v;
    }
    atomicAdd(&g_bnstat[layer * 512 + c], s);
    atomicAdd(&g_bnstat[layer * 512 + 256 + c], ss);
}

__global__ void bn_final(int layer, const float* __restrict__ gamma,
                         const float* __restrict__ beta) {
    int c = threadIdx.x;
    float sum = g_bnstat[layer * 512 + c];
    float ss  = g_bnstat[layer * 512 + 256 + c];
    float mu  = sum / (float)N_NODES;
    float var = fmaxf(ss / (float)N_NODES - mu * mu, 0.f);
    float scale = gamma[c] * rsqrtf(var + BN_EPS);
    g_bnss[layer * 512 + c]       = scale;
    g_bnss[layer * 512 + 256 + c] = beta[c] - mu * scale;
}

// ---------------- host ----------------
template <typename T>
static T* symaddr(const void* sym) {
    void* p = nullptr;
    (void)hipGetSymbolAddress(&p, sym);
    return (T*)p;
}

extern "C" void kernel_launch(void* const* d_in, const int* in_sizes, int n_in,
                              void* d_out, int out_size, void* d_ws, size_t ws_size,
                              hipStream_t stream) {
    const float* x    = (const float*)d_in[0];
    const int*   ei   = (const int*)d_in[1];
    const float* lab1 = (const float*)d_in[2];
    const float* lab2 = (const float*)d_in[3];
    const float* ew   = (const float*)d_in[4];
    const float* W0   = (const float*)d_in[5];
    const float* b0   = (const float*)d_in[6];
    const float* W1   = (const float*)d_in[7];
    const float* b1   = (const float*)d_in[8];
    const float* W2   = (const float*)d_in[9];
    const float* b2   = (const float*)d_in[10];
    const float* gg0  = (const float*)d_in[11];
    const float* be0  = (const float*)d_in[12];
    const float* gg1  = (const float*)d_in[13];
    const float* be1  = (const float*)d_in[14];

    _Float16* ph16 = symaddr<_Float16>(HIP_SYMBOL(g_h16));
    _Float16* pAh  = symaddr<_Float16>(HIP_SYMBOL(g_Ah));
    _Float16* pP   = symaddr<_Float16>(HIP_SYMBOL(g_P));
    _Float16* po40 = symaddr<_Float16>(HIP_SYMBOL(g_o40h));
    _Float16* pl80a= symaddr<_Float16>(HIP_SYMBOL(g_l80a));
    _Float16* pl80b= symaddr<_Float16>(HIP_SYMBOL(g_l80b));
    _Float16* pw0t = symaddr<_Float16>(HIP_SYMBOL(g_w0t));
    _Float16* pw1t = symaddr<_Float16>(HIP_SYMBOL(g_w1t));
    _Float16* pw2t = symaddr<_Float16>(HIP_SYMBOL(g_w2t));
    float* pdeg = symaddr<float>(HIP_SYMBOL(g_deg));
    int*   pcnt = symaddr<int>(HIP_SYMBOL(g_cnt));
    int*   pfil = symaddr<int>(HIP_SYMBOL(g_fill));
    float* pbst = symaddr<float>(HIP_SYMBOL(g_bnstat));
    float* pbss = symaddr<float>(HIP_SYMBOL(g_bnss));

    hipMemsetAsync(pdeg, 0, N_NODES * sizeof(float), stream);
    hipMemsetAsync(pcnt, 0, N_NODES * sizeof(int),   stream);
    hipMemsetAsync(pfil, 0, N_NODES * sizeof(int),   stream);
    hipMemsetAsync(pbst, 0, 4 * HID_C * sizeof(float), stream);

    // CSR build
    const int EB = (N_EDGES + 255) / 256;
    deg_count<<<EB, 256, 0, stream>>>(ei, ew);
    dinv_kernel<<<(N_NODES + 255) / 256, 256, 0, stream>>>();
    chunk_sum<<<N_CHUNK, 256, 0, stream>>>();
    chunk_scan<<<1, 1, 0, stream>>>();
    local_scan<<<N_CHUNK, 256, 0, stream>>>();
    fill_kernel<<<EB, 256, 0, stream>>>(ei, ei + N_EDGES, ew);

    // weight transposes (blocked+swizzled) + label interleave
    wtrans_blk<<<(IN_C * 256 + 255) / 256, 256, 0, stream>>>(W0, pw0t, IN_C);
    wtrans_blk<<<(HID_C * 256 + 255) / 256, 256, 0, stream>>>(W1, pw1t, HID_C);
    wtrans_out<<<(256 * 64 + 255) / 256, 256, 0, stream>>>(W2, pw2t);
    cvt_lab80<<<(N_NODES * 80 + 255) / 256, 256, 0, stream>>>(lab1, lab2, pl80a);

    const int GT64 = (N_NODES + 63) / 64;    // 782
    const int GO   = (N_NODES + 127) / 128;  // 391
    const int GB32 = (N_NODES + 31) / 32;    // 1563
    const int PB   = N_NODES / 4;            // 12500
    const int CB   = (N_NODES * 64 + 255) / 256;
    float* outf = (float*)d_out;    // fp32: out | y_hat | y_hat2

    // layer 0 (A = x fp32, converted in-register during staging)
    gemm_t<IN_C, float><<<GT64, 256, 0, stream>>>(x, pw0t, pAh, N_NODES);
    prop256h<<<PB, 256, 0, stream>>>(pAh, pP, b0);
    bn_stats16<<<GB32, 256, 0, stream>>>(pP, 0);
    bn_final<<<1, 256, 0, stream>>>(0, gg0, be0);
    bn_apply16<<<CB, 256, 0, stream>>>(pP, ph16, pbss, pbss + 256);

    // layer 1
    gemm_t<HID_C, _Float16><<<GT64, 256, 0, stream>>>(ph16, pw1t, pAh, N_NODES);
    prop256h<<<PB, 256, 0, stream>>>(pAh, pP, b1);
    bn_stats16<<<GB32, 256, 0, stream>>>(pP, 1);
    bn_final<<<1, 256, 0, stream>>>(1, gg1, be1);
    bn_apply16<<<CB, 256, 0, stream>>>(pP, ph16, pbss + 512, pbss + 768);

    // layer 2
    gemm_out_t<<<GO, 256, 0, stream>>>(ph16, pw2t, po40, N_NODES);
    prop40h<<<PB, 256, 0, stream>>>(po40, outf, b2);

    // label propagation x3 (both matrices per pass, interleaved fp16)
    prop80<false><<<PB, 256, 0, stream>>>(pl80a, pl80b, nullptr, nullptr);
    prop80<false><<<PB, 256, 0, stream>>>(pl80b, pl80a, nullptr, nullptr);
    prop80<true ><<<PB, 256, 0, stream>>>(pl80a, nullptr,
                                          outf + (size_t)N_NODES * OUT_C,
                                          outf + 2 * (size_t)N_NODES * OUT_C);
}